// Round 1
// 328.678 us; speedup vs baseline: 1.1498x; 1.1498x over previous
//
#include <hip/hip_runtime.h>

#define BOX 71
#define NF 32
#define MAX_DIST_F 35.0f

// One 32-lane group per point: lane f handles feature f.
// features layout [B,N,F] -> consecutive lanes read consecutive floats (coalesced).
// atomicAdd target grid[0, x, y, z, f] -> 32 consecutive floats per point (coalesced burst).
__global__ __launch_bounds__(256) void MakeGrid_scatter_kernel(
    const float* __restrict__ coords,
    const float* __restrict__ features,
    float* __restrict__ grid,
    int total_points)
{
    int t = blockIdx.x * blockDim.x + threadIdx.x;
    int p = t >> 5;          // point index
    int f = t & 31;          // feature index
    if (p >= total_points) return;

    // All 32 lanes of the group load the same 3 coords (L1-cached broadcast).
    float cx = coords[p * 3 + 0];
    float cy = coords[p * 3 + 1];
    float cz = coords[p * 3 + 2];

    // jnp.round = round-half-to-even; rintf matches (default RNE rounding mode).
    // GRID_RES = 1.0 so (c + 35.0f) / 1.0f == c + 35.0f exactly.
    float rx = rintf(cx + MAX_DIST_F);
    float ry = rintf(cy + MAX_DIST_F);
    float rz = rintf(cz + MAX_DIST_F);
    int gx = (int)rx;
    int gy = (int)ry;
    int gz = (int)rz;

    bool in_box = (gx >= 0) & (gx < BOX) &
                  (gy >= 0) & (gy < BOX) &
                  (gz >= 0) & (gz < BOX);
    if (!in_box) return;     // reference adds 0 at clamped index -> no-op

    float v = features[(size_t)p * NF + f];
    size_t idx = (((size_t)gx * BOX + gy) * BOX + gz) * NF + f;
    atomicAdd(grid + idx, v);  // device-scope by default on CDNA
}

extern "C" void kernel_launch(void* const* d_in, const int* in_sizes, int n_in,
                              void* d_out, int out_size, void* d_ws, size_t ws_size,
                              hipStream_t stream) {
    const float* coords   = (const float*)d_in[0];  // [B,N,3] fp32
    const float* features = (const float*)d_in[1];  // [B,N,F] fp32
    float* out = (float*)d_out;                     // [B,71,71,71,F] fp32

    // Harness re-poisons d_out to 0xAA before every timed call, so the full
    // output must be zeroed each launch.
    // out_size is a BYTE count: rocprof showed the previous
    // `out_size * sizeof(float)` memset writing 1.466 GB = 4x the 366.5 MB
    // output (WRITE_SIZE 1,431,644 KB, 241 us @ 6.08 TB/s). Memset exactly
    // out_size bytes -> ~60 us.
    hipMemsetAsync(out, 0, (size_t)out_size, stream);

    int total_points = in_sizes[0] / 3;             // B*N = 131072
    int total_threads = total_points * NF;
    int blocks = (total_threads + 255) / 256;
    MakeGrid_scatter_kernel<<<blocks, 256, 0, stream>>>(coords, features, out, total_points);
}